// Round 11
// baseline (914.485 us; speedup 1.0000x reference)
//
#include <hip/hip_runtime.h>
#include <math.h>

#define N_PTS 16384
#define K_NBR 16
#define H_DIM 64
#define TS    512    // kNN LDS tile (points)
#define CAP   144    // per-row candidate buffer (entries)

typedef unsigned long long u64;
typedef float v2f __attribute__((ext_vector_type(2)));

// prefix count of set bits of m strictly below my lane
__device__ __forceinline__ int prefix_lt(u64 m) {
    return __builtin_amdgcn_mbcnt_hi((unsigned)(m >> 32),
           __builtin_amdgcn_mbcnt_lo((unsigned)m, 0));
}
// key = (order-preserving float bits, ~idx): sorts by value desc then idx asc
__device__ __forceinline__ u64 mkkey(unsigned vbits, unsigned idx) {
    unsigned of = vbits ^ (unsigned)(((int)vbits >> 31) | 0x80000000);
    return ((u64)of << 32) | (unsigned)(~idx);
}
__device__ __forceinline__ unsigned keyidx(u64 k) { return ~(unsigned)k; }

__device__ __forceinline__ float readlane_f(float v, int l) {
    return __uint_as_float(__builtin_amdgcn_readlane(__float_as_uint(v), l));
}

// 64-lane bitonic ascending sort, float
__device__ __forceinline__ float wave_sort_f32(float v, int lane) {
#pragma unroll
    for (int k = 2; k <= 64; k <<= 1) {
#pragma unroll
        for (int j = k >> 1; j > 0; j >>= 1) {
            float o = __shfl_xor(v, j, 64);
            bool keep_min = (((lane & k) == 0) == ((lane & j) == 0));
            v = keep_min ? fminf(v, o) : fmaxf(v, o);
        }
    }
    return v;
}
// 64-lane bitonic ascending sort, u64 keys
__device__ __forceinline__ u64 wave_sort_u64(u64 v, int lane) {
#pragma unroll
    for (int k = 2; k <= 64; k <<= 1) {
#pragma unroll
        for (int j = k >> 1; j > 0; j >>= 1) {
            u64 o = __shfl_xor((unsigned long long)v, j, 64);
            bool keep_min = (((lane & k) == 0) == ((lane & j) == 0));
            u64 mn = (v < o) ? v : o;
            u64 mx = (v < o) ? o : v;
            v = keep_min ? mn : mx;
        }
    }
    return v;
}

// raise tau to 16th-largest of per-lane max VALUES, drop entries below.
// Exact: tau <= 16th-largest value seen; >=-keep retains all boundary ties
// (which have lower indices than any future candidate).
__device__ __forceinline__ int wave_compact(uint2* buf, int cnt, float* tau,
                                            int lane) {
    float lm = -INFINITY;
    for (int s = lane; s < cnt; s += 64)
        lm = fmaxf(lm, __uint_as_float(buf[s].x));
    const float tv = readlane_f(wave_sort_f32(lm, lane), 48);
    int nc = 0;
    for (int s0 = 0; s0 < cnt; s0 += 64) {
        const int s = s0 + lane;
        uint2 e = make_uint2(0u, 0u);
        bool keep = false;
        if (s < cnt) { e = buf[s]; keep = (__uint_as_float(e.x) >= tv); }
        const u64 km = __ballot(keep);
        if (keep) buf[nc + prefix_lt(km)] = e;  // write idx <= read idx: safe
        nc += (int)__popcll(km);
    }
    *tau = tv;
    return nc;
}

// ---------------- xx[i] = sum(x[i]^2), mimicking numpy squares-then-sum ----
__global__ __launch_bounds__(256) void xx_kernel(const float4* __restrict__ x4,
                                                 float* __restrict__ xx) {
    int i = blockIdx.x * 256 + threadIdx.x;
    float4 v = x4[i];
    {
#pragma clang fp contract(off)
        float s0 = v.x * v.x;
        float s1 = v.y * v.y;
        float s2 = v.z * v.z;
        float s3 = v.w * v.w;
        xx[i] = ((s0 + s1) + s2) + s3;
    }
}

// ---------------- brute-force kNN: 2 rows/wave, pk-fp32 candidate PAIRS ----
// (proven R9 kernel, 141 us) x staged component-transposed: ds_read_b64
// yields candidates (2c,2c+1) pre-packed for v_pk_fma_f32.
__global__ __launch_bounds__(256, 8) void knn_kernel(
        const float4* __restrict__ x4,
        const float* __restrict__ xx,
        int* __restrict__ knn) {
    __shared__ float xsc[4][TS];           // 8 KB, component-transposed
    __shared__ float nxxs[TS];             // 2 KB
    __shared__ uint2 buf[8][CAP];          // 9 KB   (19.25 KB -> 8 blk/CU)
    const int lane = threadIdx.x & 63;
    const int wave = threadIdx.x >> 6;
    const int row0 = blockIdx.x * 8 + wave * 2;

    float4 y[2]; float nxxi[2];
    uint2* bufr[2];
#pragma unroll
    for (int r = 0; r < 2; ++r) {
        const float4 t0 = x4[row0 + r];
        y[r] = make_float4(2.0f * t0.x, 2.0f * t0.y, 2.0f * t0.z, 2.0f * t0.w);
        nxxi[r] = -xx[row0 + r];
        bufr[r] = &buf[wave * 2 + r][0];
    }
    float tau[2]; int cnt[2];

    // distance pair for candidates (cb+2*lane, cb+2*lane+1), e = local offset
    auto pair_p = [&](int e, int r) -> v2f {
        const v2f ax = *(const v2f*)&xsc[0][e];
        const v2f ay = *(const v2f*)&xsc[1][e];
        const v2f az = *(const v2f*)&xsc[2][e];
        const v2f aw = *(const v2f*)&xsc[3][e];
        const v2f nx = *(const v2f*)&nxxs[e];
        v2f acc = nx + (v2f){nxxi[r], nxxi[r]};
        acc = __builtin_elementwise_fma(ax, (v2f){y[r].x, y[r].x}, acc);
        acc = __builtin_elementwise_fma(ay, (v2f){y[r].y, y[r].y}, acc);
        acc = __builtin_elementwise_fma(az, (v2f){y[r].z, y[r].z}, acc);
        acc = __builtin_elementwise_fma(aw, (v2f){y[r].w, y[r].w}, acc);
        return acc;
    };

    // ---- stage tile 0 ----
    for (int i = threadIdx.x; i < TS; i += 256) {
        const float4 v = x4[i];
        xsc[0][i] = v.x; xsc[1][i] = v.y; xsc[2][i] = v.z; xsc[3][i] = v.w;
        nxxs[i] = -xx[i];
    }
    __syncthreads();

    // ---- seed from first 128 candidates ----
    // tau = 16th-largest of 64 pair-maxima m16: the top-16 maxima are 16
    // distinct candidates all >= m16, so p16(128) >= m16 -> tau safe.
    {
        const int e = 2 * lane;
#pragma unroll
        for (int r = 0; r < 2; ++r) {
            const v2f pp = pair_p(e, r);
            const float mx = fmaxf(pp.x, pp.y);
            tau[r] = readlane_f(wave_sort_f32(mx, lane), 48);
            const u64 ma = __ballot(pp.x >= tau[r]);   // >= keeps ties
            const u64 mb = __ballot(pp.y >= tau[r]);
            const int ca = (int)__popcll(ma);
            if (pp.x >= tau[r])
                bufr[r][prefix_lt(ma)] =
                    make_uint2(__float_as_uint(pp.x), (unsigned)e);
            if (pp.y >= tau[r])
                bufr[r][ca + prefix_lt(mb)] =
                    make_uint2(__float_as_uint(pp.y), (unsigned)(e + 1));
            cnt[r] = ca + (int)__popcll(mb);
        }
    }

    // ---- main stream ----
    auto do_iter = [&](int cbase) {          // 128 candidates at cbase
        const int e = (cbase & (TS - 1)) + 2 * lane;
        v2f pp[2]; u64 mm[2];
#pragma unroll
        for (int r = 0; r < 2; ++r) {
            pp[r] = pair_p(e, r);
            mm[r] = __ballot(fmaxf(pp[r].x, pp[r].y) > tau[r]);
        }
        if (mm[0] | mm[1]) {                 // wave-uniform, rare post-seed
#pragma unroll
            for (int r = 0; r < 2; ++r) {
                if (mm[r]) {
                    u64 ma = __ballot(pp[r].x > tau[r]);
                    u64 mb = __ballot(pp[r].y > tau[r]);
                    int add = (int)__popcll(ma) + (int)__popcll(mb);
                    if (cnt[r] + add > CAP) {  // compact only when needed
                        cnt[r] = wave_compact(bufr[r], cnt[r], &tau[r], lane);
                        ma = __ballot(pp[r].x > tau[r]);
                        mb = __ballot(pp[r].y > tau[r]);
                        add = (int)__popcll(ma) + (int)__popcll(mb);
                    }
                    const int ca = (int)__popcll(ma);
                    if (pp[r].x > tau[r])
                        bufr[r][cnt[r] + prefix_lt(ma)] =
                            make_uint2(__float_as_uint(pp[r].x),
                                       (unsigned)(cbase + 2 * lane));
                    if (pp[r].y > tau[r])
                        bufr[r][cnt[r] + ca + prefix_lt(mb)] =
                            make_uint2(__float_as_uint(pp[r].y),
                                       (unsigned)(cbase + 2 * lane + 1));
                    cnt[r] += add;
                }
            }
        }
    };

    // rest of tile 0 (pair-iters 1..3)
#pragma unroll
    for (int j = 1; j < TS / 128; ++j) do_iter(j * 128);

    for (int t = 1; t < N_PTS / TS; ++t) {
        const int base = t * TS;
        __syncthreads();
        for (int i = threadIdx.x; i < TS; i += 256) {
            const float4 v = x4[base + i];
            xsc[0][i] = v.x; xsc[1][i] = v.y; xsc[2][i] = v.z; xsc[3][i] = v.w;
            nxxs[i] = -xx[base + i];
        }
        __syncthreads();
#pragma unroll
        for (int j = 0; j < TS / 128; ++j) do_iter(base + j * 128);
    }

    // final: compact, one u64-key bitonic sort, lanes 48..63 = top-16
#pragma unroll
    for (int r = 0; r < 2; ++r) {
        const int c2 = wave_compact(bufr[r], cnt[r], &tau[r], lane);
        u64 key = 0;                               // sentinel < any real key
        if (lane < c2) {
            const uint2 e = bufr[r][lane];
            key = mkkey(e.x, e.y);
        }
        key = wave_sort_u64(key, lane);
        if (lane >= 48)
            knn[(row0 + r) * K_NBR + (lane - 48)] = (int)keyidx(key);
    }
}

// ---------------- edge-feature MLP: parallel neighbor gather ---------------
// Layer1's old serial chain (knn[k] -> x4[nb], 32 dependent uniform loads)
// is replaced by one coalesced idx load + one parallel 16-lane gather into
// 2 KB LDS; layer1 then reads broadcast b128. h = hb + sum w1[c]*xj[c] with
// hb = b1 + sum (w1[4+c]-w1[c])*xi[c] (algebraic fold, fp-safe vs threshold).
__global__ __launch_bounds__(512, 4) void mlp_kernel(
        const float4* __restrict__ x4,
        const int* __restrict__ knn,
        const float4* __restrict__ W2f4,
        const float* __restrict__ W1,
        const float* __restrict__ b1,
        const float* __restrict__ b2,
        float* __restrict__ out) {
    __shared__ __align__(16) float4 w2s[16][64];     // 16 KB, h4-major
    __shared__ __align__(16) float  h1s[8][16][68];  // ~34 KB, per-wave
    __shared__ __align__(16) float4 xjs[8][16];      // 2 KB, per-wave gather
    const int lane = threadIdx.x & 63;
    const int wave = threadIdx.x >> 6;
    const int kq   = lane >> 4;
    const int gp   = lane & 15;
    const int p0   = (blockIdx.x * 8 + wave) * 2;    // 2 points per wave

    for (int q = threadIdx.x; q < 1024; q += 512)
        w2s[q & 15][q >> 4] = W2f4[q];               // w2s[h4][g]
    __syncthreads();

    float w1r[8];
#pragma unroll
    for (int c = 0; c < 8; ++c) w1r[c] = W1[lane * 8 + c];
    const float b1r = b1[lane];
    float b2r[4];
#pragma unroll
    for (int gq = 0; gq < 4; ++gq) b2r[gq] = b2[gq * 16 + gp];

    // layer 2 accumulators (packed pairs over h), both points
    v2f acc[2][4][4];
#pragma unroll
    for (int pp = 0; pp < 2; ++pp)
#pragma unroll
        for (int kk = 0; kk < 4; ++kk)
#pragma unroll
            for (int gq = 0; gq < 4; ++gq)
                acc[pp][kk][gq] = (v2f){b2r[gq], 0.0f};

#pragma unroll
    for (int pp = 0; pp < 2; ++pp) {
        const int p = p0 + pp;
        const float4 xi = x4[p];

        // parallel gather: 16 indices coalesced, 16 x4 loads in flight at once
        if (lane < K_NBR) {
            const int nb = knn[p * K_NBR + lane];
            xjs[wave][lane] = x4[nb];
        }
        // wave-private LDS + in-wave vmcnt/lgkmcnt ordering: no barrier

        // hb = b1 + sum_c (w1[4+c]-w1[c])*xi_c
        float hb = b1r;
        hb = fmaf(w1r[4] - w1r[0], xi.x, hb);
        hb = fmaf(w1r[5] - w1r[1], xi.y, hb);
        hb = fmaf(w1r[6] - w1r[2], xi.z, hb);
        hb = fmaf(w1r[7] - w1r[3], xi.w, hb);

        // layer 1 (lane = hidden feature h): 1 broadcast b128 + 4 fma per k
#pragma unroll
        for (int k = 0; k < K_NBR; ++k) {
            const float4 xj = xjs[wave][k];
            float h = hb;
            h = fmaf(w1r[0], xj.x, h);
            h = fmaf(w1r[1], xj.y, h);
            h = fmaf(w1r[2], xj.z, h);
            h = fmaf(w1r[3], xj.w, h);
            h1s[wave][k][lane] = fmaxf(h, 0.0f);
        }

        // layer 2: acc[pp][kk][gq] += w2[g][h]*h1[k][h] (pk-fp32)
#pragma unroll
        for (int h4 = 0; h4 < 16; ++h4) {
            float4 w4[4];
#pragma unroll
            for (int gq = 0; gq < 4; ++gq) w4[gq] = w2s[h4][gq * 16 + gp];
#pragma unroll
            for (int kk = 0; kk < 4; ++kk) {
                const float4 hv =
                    *(const float4*)&h1s[wave][kq * 4 + kk][h4 * 4];
#pragma unroll
                for (int gq = 0; gq < 4; ++gq) {
                    acc[pp][kk][gq] = __builtin_elementwise_fma(
                        (v2f){hv.x, hv.y}, (v2f){w4[gq].x, w4[gq].y},
                        acc[pp][kk][gq]);
                    acc[pp][kk][gq] = __builtin_elementwise_fma(
                        (v2f){hv.z, hv.w}, (v2f){w4[gq].z, w4[gq].w},
                        acc[pp][kk][gq]);
                }
            }
        }
    }

#pragma unroll
    for (int pp = 0; pp < 2; ++pp) {
        float s[4];
#pragma unroll
        for (int gq = 0; gq < 4; ++gq) {
            s[gq] = 0.0f;
#pragma unroll
            for (int kk = 0; kk < 4; ++kk) {
                const float v = acc[pp][kk][gq].x + acc[pp][kk][gq].y;
                s[gq] += fmaxf(v, 0.0f);
            }
        }
#pragma unroll
        for (int off = 16; off <= 32; off <<= 1)
#pragma unroll
            for (int gq = 0; gq < 4; ++gq)
                s[gq] += __shfl_xor(s[gq], off, 64);

        out[(p0 + pp) * H_DIM + kq * 16 + gp] = s[kq] * (1.0f / 16.0f);
    }
}

extern "C" void kernel_launch(void* const* d_in, const int* in_sizes, int n_in,
                              void* d_out, int out_size, void* d_ws, size_t ws_size,
                              hipStream_t stream) {
    (void)in_sizes; (void)n_in; (void)out_size; (void)ws_size;
    const float* x  = (const float*)d_in[0];
    const float* W1 = (const float*)d_in[1];
    const float* b1 = (const float*)d_in[2];
    const float* W2 = (const float*)d_in[3];
    const float* b2 = (const float*)d_in[4];
    float* out = (float*)d_out;

    float* xx  = (float*)d_ws;                                  // N floats
    int*   knn = (int*)((char*)d_ws + N_PTS * sizeof(float));   // N*K ints

    const float4* x4 = (const float4*)x;

    xx_kernel <<<N_PTS / 256, 256, 0, stream>>>(x4, xx);
    knn_kernel<<<N_PTS / 8,   256, 0, stream>>>(x4, xx, knn);
    mlp_kernel<<<N_PTS / 16,  512, 0, stream>>>(
        x4, knn, (const float4*)W2, W1, b1, b2, out);
}

// Round 12
// 214.937 us; speedup vs baseline: 4.2547x; 4.2547x over previous
//
#include <hip/hip_runtime.h>
#include <math.h>

#define N_PTS 16384
#define K_NBR 16
#define H_DIM 64
#define TS    512    // kNN LDS tile (points)
#define CAP   144    // per-row candidate buffer (entries)

typedef unsigned long long u64;
typedef float v2f __attribute__((ext_vector_type(2)));

// prefix count of set bits of m strictly below my lane
__device__ __forceinline__ int prefix_lt(u64 m) {
    return __builtin_amdgcn_mbcnt_hi((unsigned)(m >> 32),
           __builtin_amdgcn_mbcnt_lo((unsigned)m, 0));
}
// key = (order-preserving float bits, ~idx): sorts by value desc then idx asc
__device__ __forceinline__ u64 mkkey(unsigned vbits, unsigned idx) {
    unsigned of = vbits ^ (unsigned)(((int)vbits >> 31) | 0x80000000);
    return ((u64)of << 32) | (unsigned)(~idx);
}
__device__ __forceinline__ unsigned keyidx(u64 k) { return ~(unsigned)k; }

__device__ __forceinline__ float readlane_f(float v, int l) {
    return __uint_as_float(__builtin_amdgcn_readlane(__float_as_uint(v), l));
}

// 64-lane bitonic ascending sort, float
__device__ __forceinline__ float wave_sort_f32(float v, int lane) {
#pragma unroll
    for (int k = 2; k <= 64; k <<= 1) {
#pragma unroll
        for (int j = k >> 1; j > 0; j >>= 1) {
            float o = __shfl_xor(v, j, 64);
            bool keep_min = (((lane & k) == 0) == ((lane & j) == 0));
            v = keep_min ? fminf(v, o) : fmaxf(v, o);
        }
    }
    return v;
}
// 64-lane bitonic ascending sort, u64 keys
__device__ __forceinline__ u64 wave_sort_u64(u64 v, int lane) {
#pragma unroll
    for (int k = 2; k <= 64; k <<= 1) {
#pragma unroll
        for (int j = k >> 1; j > 0; j >>= 1) {
            u64 o = __shfl_xor((unsigned long long)v, j, 64);
            bool keep_min = (((lane & k) == 0) == ((lane & j) == 0));
            u64 mn = (v < o) ? v : o;
            u64 mx = (v < o) ? o : v;
            v = keep_min ? mn : mx;
        }
    }
    return v;
}

// raise tau to 16th-largest of per-lane max VALUES, drop entries below.
// Exact: tau <= 16th-largest value seen; >=-keep retains all boundary ties
// (which have lower indices than any future candidate).
__device__ __forceinline__ int wave_compact(uint2* buf, int cnt, float* tau,
                                            int lane) {
    float lm = -INFINITY;
    for (int s = lane; s < cnt; s += 64)
        lm = fmaxf(lm, __uint_as_float(buf[s].x));
    const float tv = readlane_f(wave_sort_f32(lm, lane), 48);
    int nc = 0;
    for (int s0 = 0; s0 < cnt; s0 += 64) {
        const int s = s0 + lane;
        uint2 e = make_uint2(0u, 0u);
        bool keep = false;
        if (s < cnt) { e = buf[s]; keep = (__uint_as_float(e.x) >= tv); }
        const u64 km = __ballot(keep);
        if (keep) buf[nc + prefix_lt(km)] = e;  // write idx <= read idx: safe
        nc += (int)__popcll(km);
    }
    *tau = tv;
    return nc;
}

// ---------------- xx[i] = sum(x[i]^2), mimicking numpy squares-then-sum ----
__global__ __launch_bounds__(256) void xx_kernel(const float4* __restrict__ x4,
                                                 float* __restrict__ xx) {
    int i = blockIdx.x * 256 + threadIdx.x;
    float4 v = x4[i];
    {
#pragma clang fp contract(off)
        float s0 = v.x * v.x;
        float s1 = v.y * v.y;
        float s2 = v.z * v.z;
        float s3 = v.w * v.w;
        xx[i] = ((s0 + s1) + s2) + s3;
    }
}

// ---------------- brute-force kNN: 2 rows/wave, pk-fp32 candidate PAIRS ----
// (proven R9 kernel, 141 us) x staged component-transposed: ds_read_b64
// yields candidates (2c,2c+1) pre-packed for v_pk_fma_f32.
__global__ __launch_bounds__(256, 8) void knn_kernel(
        const float4* __restrict__ x4,
        const float* __restrict__ xx,
        int* __restrict__ knn) {
    __shared__ float xsc[4][TS];           // 8 KB, component-transposed
    __shared__ float nxxs[TS];             // 2 KB
    __shared__ uint2 buf[8][CAP];          // 9 KB   (19.25 KB -> 8 blk/CU)
    const int lane = threadIdx.x & 63;
    const int wave = threadIdx.x >> 6;
    const int row0 = blockIdx.x * 8 + wave * 2;

    float4 y[2]; float nxxi[2];
    uint2* bufr[2];
#pragma unroll
    for (int r = 0; r < 2; ++r) {
        const float4 t0 = x4[row0 + r];
        y[r] = make_float4(2.0f * t0.x, 2.0f * t0.y, 2.0f * t0.z, 2.0f * t0.w);
        nxxi[r] = -xx[row0 + r];
        bufr[r] = &buf[wave * 2 + r][0];
    }
    float tau[2]; int cnt[2];

    // distance pair for candidates (cb+2*lane, cb+2*lane+1), e = local offset
    auto pair_p = [&](int e, int r) -> v2f {
        const v2f ax = *(const v2f*)&xsc[0][e];
        const v2f ay = *(const v2f*)&xsc[1][e];
        const v2f az = *(const v2f*)&xsc[2][e];
        const v2f aw = *(const v2f*)&xsc[3][e];
        const v2f nx = *(const v2f*)&nxxs[e];
        v2f acc = nx + (v2f){nxxi[r], nxxi[r]};
        acc = __builtin_elementwise_fma(ax, (v2f){y[r].x, y[r].x}, acc);
        acc = __builtin_elementwise_fma(ay, (v2f){y[r].y, y[r].y}, acc);
        acc = __builtin_elementwise_fma(az, (v2f){y[r].z, y[r].z}, acc);
        acc = __builtin_elementwise_fma(aw, (v2f){y[r].w, y[r].w}, acc);
        return acc;
    };

    // ---- stage tile 0 ----
    for (int i = threadIdx.x; i < TS; i += 256) {
        const float4 v = x4[i];
        xsc[0][i] = v.x; xsc[1][i] = v.y; xsc[2][i] = v.z; xsc[3][i] = v.w;
        nxxs[i] = -xx[i];
    }
    __syncthreads();

    // ---- seed from first 128 candidates ----
    // tau = 16th-largest of 64 pair-maxima m16: the top-16 maxima are 16
    // distinct candidates all >= m16, so p16(128) >= m16 -> tau safe.
    {
        const int e = 2 * lane;
#pragma unroll
        for (int r = 0; r < 2; ++r) {
            const v2f pp = pair_p(e, r);
            const float mx = fmaxf(pp.x, pp.y);
            tau[r] = readlane_f(wave_sort_f32(mx, lane), 48);
            const u64 ma = __ballot(pp.x >= tau[r]);   // >= keeps ties
            const u64 mb = __ballot(pp.y >= tau[r]);
            const int ca = (int)__popcll(ma);
            if (pp.x >= tau[r])
                bufr[r][prefix_lt(ma)] =
                    make_uint2(__float_as_uint(pp.x), (unsigned)e);
            if (pp.y >= tau[r])
                bufr[r][ca + prefix_lt(mb)] =
                    make_uint2(__float_as_uint(pp.y), (unsigned)(e + 1));
            cnt[r] = ca + (int)__popcll(mb);
        }
    }

    // ---- main stream ----
    auto do_iter = [&](int cbase) {          // 128 candidates at cbase
        const int e = (cbase & (TS - 1)) + 2 * lane;
        v2f pp[2]; u64 mm[2];
#pragma unroll
        for (int r = 0; r < 2; ++r) {
            pp[r] = pair_p(e, r);
            mm[r] = __ballot(fmaxf(pp[r].x, pp[r].y) > tau[r]);
        }
        if (mm[0] | mm[1]) {                 // wave-uniform, rare post-seed
#pragma unroll
            for (int r = 0; r < 2; ++r) {
                if (mm[r]) {
                    u64 ma = __ballot(pp[r].x > tau[r]);
                    u64 mb = __ballot(pp[r].y > tau[r]);
                    int add = (int)__popcll(ma) + (int)__popcll(mb);
                    if (cnt[r] + add > CAP) {  // compact only when needed
                        cnt[r] = wave_compact(bufr[r], cnt[r], &tau[r], lane);
                        ma = __ballot(pp[r].x > tau[r]);
                        mb = __ballot(pp[r].y > tau[r]);
                        add = (int)__popcll(ma) + (int)__popcll(mb);
                    }
                    const int ca = (int)__popcll(ma);
                    if (pp[r].x > tau[r])
                        bufr[r][cnt[r] + prefix_lt(ma)] =
                            make_uint2(__float_as_uint(pp[r].x),
                                       (unsigned)(cbase + 2 * lane));
                    if (pp[r].y > tau[r])
                        bufr[r][cnt[r] + ca + prefix_lt(mb)] =
                            make_uint2(__float_as_uint(pp[r].y),
                                       (unsigned)(cbase + 2 * lane + 1));
                    cnt[r] += add;
                }
            }
        }
    };

    // rest of tile 0 (pair-iters 1..3)
#pragma unroll
    for (int j = 1; j < TS / 128; ++j) do_iter(j * 128);

    for (int t = 1; t < N_PTS / TS; ++t) {
        const int base = t * TS;
        __syncthreads();
        for (int i = threadIdx.x; i < TS; i += 256) {
            const float4 v = x4[base + i];
            xsc[0][i] = v.x; xsc[1][i] = v.y; xsc[2][i] = v.z; xsc[3][i] = v.w;
            nxxs[i] = -xx[base + i];
        }
        __syncthreads();
#pragma unroll
        for (int j = 0; j < TS / 128; ++j) do_iter(base + j * 128);
    }

    // final: compact, one u64-key bitonic sort, lanes 48..63 = top-16
#pragma unroll
    for (int r = 0; r < 2; ++r) {
        const int c2 = wave_compact(bufr[r], cnt[r], &tau[r], lane);
        u64 key = 0;                               // sentinel < any real key
        if (lane < c2) {
            const uint2 e = bufr[r][lane];
            key = mkkey(e.x, e.y);
        }
        key = wave_sort_u64(key, lane);
        if (lane >= 48)
            knn[(row0 + r) * K_NBR + (lane - 48)] = (int)keyidx(key);
    }
}

// ---------------- edge-feature MLP: parallel gather + hoisted W2 -----------
// 4-wave blocks, 2 points/wave. __launch_bounds__(256,2): VGPR cap >=256
// under either launch-bounds interpretation -> acc[2][4][4] v2f (64 regs)
// stays in registers (R11's (512,4) capped VGPR at 64 -> 2 GB spill traffic).
// Layer1: one coalesced idx load + 32-lane parallel gather into LDS, then
// broadcast b128 reads. Layer2: h4-outer, w4 hoisted across both points
// (96 LDS reads/pt). LDS 53 KB -> 3 blk/CU = 12 waves/CU (LDS-pipe bound).
__global__ __launch_bounds__(256, 2) void mlp_kernel(
        const float4* __restrict__ x4,
        const int* __restrict__ knn,
        const float4* __restrict__ W2f4,
        const float* __restrict__ W1,
        const float* __restrict__ b1,
        const float* __restrict__ b2,
        float* __restrict__ out) {
    __shared__ __align__(16) float4 w2s[16][64];     // 16 KB, h4-major
    __shared__ __align__(16) float  h1s[4][32][68];  // 34 KB, per-wave
    __shared__ __align__(16) float4 xjs[4][32];      // 2 KB, per-wave gather
    const int lane = threadIdx.x & 63;
    const int wave = threadIdx.x >> 6;
    const int kq   = lane >> 4;
    const int gp   = lane & 15;
    const int p0   = (blockIdx.x * 4 + wave) * 2;    // 2 points per wave

    for (int q = threadIdx.x; q < 1024; q += 256)
        w2s[q & 15][q >> 4] = W2f4[q];               // w2s[h4][g]
    __syncthreads();

    float w1r[8];
#pragma unroll
    for (int c = 0; c < 8; ++c) w1r[c] = W1[lane * 8 + c];
    const float b1r = b1[lane];
    float b2r[4];
#pragma unroll
    for (int gq = 0; gq < 4; ++gq) b2r[gq] = b2[gq * 16 + gp];

    // parallel gather: 32 indices coalesced, 32 x4 loads in flight at once
    if (lane < 32) {
        const int pp = lane >> 4;
        const int nb = knn[(p0 + pp) * K_NBR + (lane & 15)];
        xjs[wave][lane] = x4[nb];
    }
    // wave-private LDS + in-wave vmcnt/lgkmcnt ordering: no barrier

    // layer 1 for both points (lane = hidden feature h)
#pragma unroll
    for (int pp = 0; pp < 2; ++pp) {
        const float4 xi = x4[p0 + pp];
        // hb = b1 + sum_c (w1[4+c]-w1[c])*xi_c  (algebraic fold, fp-safe)
        float hb = b1r;
        hb = fmaf(w1r[4] - w1r[0], xi.x, hb);
        hb = fmaf(w1r[5] - w1r[1], xi.y, hb);
        hb = fmaf(w1r[6] - w1r[2], xi.z, hb);
        hb = fmaf(w1r[7] - w1r[3], xi.w, hb);
#pragma unroll
        for (int k = 0; k < K_NBR; ++k) {
            const float4 xj = xjs[wave][pp * 16 + k];
            float h = hb;
            h = fmaf(w1r[0], xj.x, h);
            h = fmaf(w1r[1], xj.y, h);
            h = fmaf(w1r[2], xj.z, h);
            h = fmaf(w1r[3], xj.w, h);
            h1s[wave][pp * 16 + k][lane] = fmaxf(h, 0.0f);
        }
    }

    // layer 2: acc[pp][kk][gq] (packed pairs over h), h4-outer, w4 hoisted
    v2f acc[2][4][4];
#pragma unroll
    for (int pp = 0; pp < 2; ++pp)
#pragma unroll
        for (int kk = 0; kk < 4; ++kk)
#pragma unroll
            for (int gq = 0; gq < 4; ++gq)
                acc[pp][kk][gq] = (v2f){b2r[gq], 0.0f};

#pragma unroll
    for (int h4 = 0; h4 < 16; ++h4) {
        float4 w4[4];
#pragma unroll
        for (int gq = 0; gq < 4; ++gq) w4[gq] = w2s[h4][gq * 16 + gp];
#pragma unroll
        for (int pp = 0; pp < 2; ++pp) {
#pragma unroll
            for (int kk = 0; kk < 4; ++kk) {
                const float4 hv =
                    *(const float4*)&h1s[wave][pp * 16 + kq * 4 + kk][h4 * 4];
#pragma unroll
                for (int gq = 0; gq < 4; ++gq) {
                    acc[pp][kk][gq] = __builtin_elementwise_fma(
                        (v2f){hv.x, hv.y}, (v2f){w4[gq].x, w4[gq].y},
                        acc[pp][kk][gq]);
                    acc[pp][kk][gq] = __builtin_elementwise_fma(
                        (v2f){hv.z, hv.w}, (v2f){w4[gq].z, w4[gq].w},
                        acc[pp][kk][gq]);
                }
            }
        }
    }

#pragma unroll
    for (int pp = 0; pp < 2; ++pp) {
        float s[4];
#pragma unroll
        for (int gq = 0; gq < 4; ++gq) {
            s[gq] = 0.0f;
#pragma unroll
            for (int kk = 0; kk < 4; ++kk) {
                const float v = acc[pp][kk][gq].x + acc[pp][kk][gq].y;
                s[gq] += fmaxf(v, 0.0f);
            }
        }
#pragma unroll
        for (int off = 16; off <= 32; off <<= 1)
#pragma unroll
            for (int gq = 0; gq < 4; ++gq)
                s[gq] += __shfl_xor(s[gq], off, 64);

        out[(p0 + pp) * H_DIM + kq * 16 + gp] = s[kq] * (1.0f / 16.0f);
    }
}

extern "C" void kernel_launch(void* const* d_in, const int* in_sizes, int n_in,
                              void* d_out, int out_size, void* d_ws, size_t ws_size,
                              hipStream_t stream) {
    (void)in_sizes; (void)n_in; (void)out_size; (void)ws_size;
    const float* x  = (const float*)d_in[0];
    const float* W1 = (const float*)d_in[1];
    const float* b1 = (const float*)d_in[2];
    const float* W2 = (const float*)d_in[3];
    const float* b2 = (const float*)d_in[4];
    float* out = (float*)d_out;

    float* xx  = (float*)d_ws;                                  // N floats
    int*   knn = (int*)((char*)d_ws + N_PTS * sizeof(float));   // N*K ints

    const float4* x4 = (const float4*)x;

    xx_kernel <<<N_PTS / 256, 256, 0, stream>>>(x4, xx);
    knn_kernel<<<N_PTS / 8,   256, 0, stream>>>(x4, xx, knn);
    mlp_kernel<<<N_PTS / 8,   256, 0, stream>>>(
        x4, knn, (const float4*)W2, W1, b1, b2, out);
}